// Round 1
// 339.066 us; speedup vs baseline: 1.0120x; 1.0120x over previous
//
#include <hip/hip_runtime.h>
#include <stdint.h>

namespace {

constexpr int SEQ    = 250;
constexpr int SPAN   = 50;
constexpr int NSPANS = 3;
constexpr int NATT   = 15;
constexpr int QS     = 95;   // QRS_START
constexpr int QE     = 155;  // QRS_END
constexpr int NB     = 16384;
constexpr int NCH    = 12;
constexpr uint32_t HI = 200; // exclusive upper bound for starts

struct U2 { uint32_t a, b; };

// Threefry-2x32, 20 rounds — bit-exact replica of jax/_src/prng.py
__host__ __device__ constexpr U2 tf2x32(uint32_t k0, uint32_t k1,
                                        uint32_t x0, uint32_t x1) {
  uint32_t ks[3] = { k0, k1, k0 ^ k1 ^ 0x1BD11BDAu };
  uint32_t rot[2][4] = { {13u, 15u, 26u, 6u}, {17u, 29u, 16u, 24u} };
  x0 += ks[0];
  x1 += ks[1];
  for (int i = 0; i < 5; ++i) {
    for (int j = 0; j < 4; ++j) {
      uint32_t r = rot[i & 1][j];
      x0 += x1;
      x1 = (x1 << r) | (x1 >> (32u - r));
      x1 ^= x0;
    }
    x0 += ks[(i + 1) % 3];
    x1 += ks[(i + 2) % 3] + (uint32_t)(i + 1);
  }
  return U2{x0, x1};
}

// ---- PARTITIONABLE threefry semantics (jax_threefry_partitionable=True):
//   split(key, n): subkey j = (tf(key,0,j).a, tf(key,0,j).b)   [no XOR]
//   random_bits(key, 32, shape): out[i] = tf(key,0,i).a ^ tf(key,0,i).b [XOR]
//
// jax.random.key(42) => raw key (0, 42)
constexpr U2 SK1 = tf2x32(0u, 42u, 0u, 0u);  // k1: uniform(use_physio)
constexpr U2 SK2 = tf2x32(0u, 42u, 0u, 1u);  // k2: candidate randint
constexpr U2 SK3 = tf2x32(0u, 42u, 0u, 2u);  // k3: fallback randint

// randint's internal split(key, 2): hi-bits key counter (0,0), lo-bits (0,1)
constexpr U2 K2H = tf2x32(SK2.a, SK2.b, 0u, 0u);
constexpr U2 K2L = tf2x32(SK2.a, SK2.b, 0u, 1u);
constexpr U2 K3H = tf2x32(SK3.a, SK3.b, 0u, 0u);
constexpr U2 K3L = tf2x32(SK3.a, SK3.b, 0u, 1u);

// 32-bit random bits draw, partitionable path: XOR of both output words
__device__ __forceinline__ uint32_t rbit(U2 k, uint32_t idx) {
  U2 r = tf2x32(k.a, k.b, 0u, idx);
  return r.a ^ r.b;
}

// jax randint(0,200): multiplier = (2^16 % 200)^2 % 200 = 96
__device__ __forceinline__ uint32_t draw200(uint32_t h, uint32_t l) {
  return ((h % HI) * 96u + (l % HI)) % HI;
}

__global__ void k_starts(int* __restrict__ starts) {
  constexpr uint32_t NU = (uint32_t)NB * NSPANS;  // 49152
  int t = blockIdx.x * blockDim.x + threadIdx.x;
  if (t >= (int)NU) return;

  // use_physio = uniform(k1) < 0.8 ; u = bitcast((bits>>9)|0x3f800000) - 1
  uint32_t ub = rbit(SK1, (uint32_t)t);
  float u = __uint_as_float((ub >> 9) | 0x3f800000u) - 1.0f;
  bool physio = (u < 0.8f);

  int chosen = -1;
  for (int a = 0; a < NATT; ++a) {
    uint32_t idx = (uint32_t)t * NATT + (uint32_t)a;  // flat (B,S,A) index
    uint32_t h = rbit(K2H, idx);
    uint32_t l = rbit(K2L, idx);
    int cand = (int)draw200(h, l);
    // ends = min(cand+50, 250) <= 249; no_overlap = (end<=95) | (cand>=155)
    bool no_ov = (cand + SPAN <= QS) || (cand >= QE);
    if (no_ov || !physio) { chosen = cand; break; }  // argmax = first valid
  }

  int st;
  if (chosen >= 0) {
    st = chosen;
  } else {
    uint32_t h = rbit(K3H, (uint32_t)t);
    uint32_t l = rbit(K3L, (uint32_t)t);
    st = (int)draw200(h, l);
  }
  starts[t] = st;
}

// Fused output kernel. Grid covers both outputs in float4 units:
//   tid < NV4X            : masked_x   (16384*12*250 / 4 = 12,288,000)
//   NV4X <= tid < NV4T    : masks      (16384*250 / 4    =  1,024,000)
// NV4X / 256 = 48000 exactly, so the region branch is block-uniform.
//
// Read-skip: if all 4 positions of a thread's float4 are masked, the x load
// is skipped. Masked runs are 50-150 contiguous floats, so many full 128B
// lines have no active lane -> never fetched from HBM (~30-40% read savings).
constexpr int NV4X = NB * NCH * SEQ / 4;  // 12,288,000
constexpr int NV4M = NB * SEQ / 4;        //  1,024,000
constexpr int NV4T = NV4X + NV4M;         // 13,312,000 = 52000 * 256

__global__ void k_fused(const float4* __restrict__ x4, float4* __restrict__ o4,
                        float4* __restrict__ m4, const int* __restrict__ starts) {
  int tid = blockIdx.x * blockDim.x + threadIdx.x;
  if (tid < NV4X) {
    // ---- masked_x path. 3000 % 4 == 0 so a float4 never crosses a batch
    // boundary (channel-row crossings are fine: mask depends only on pos).
    int f = tid << 2;
    int b = f / (NCH * SEQ);
    int r = f - b * (NCH * SEQ);
    int pos0 = r % SEQ;
    int s0 = starts[b * 3 + 0];
    int s1 = starts[b * 3 + 1];
    int s2 = starts[b * 3 + 2];
    bool mm[4];
    int nmask = 0;
#pragma unroll
    for (int j = 0; j < 4; ++j) {
      int p = pos0 + j;
      if (p >= SEQ) p -= SEQ;  // wrap into next channel row (same batch)
      bool m = ((unsigned)(p - s0) < (unsigned)SPAN) ||
               ((unsigned)(p - s1) < (unsigned)SPAN) ||
               ((unsigned)(p - s2) < (unsigned)SPAN);
      mm[j] = m;
      nmask += (int)m;
    }
    if (nmask == 4) {
      // fully masked: no need to read x at all
      o4[tid] = make_float4(0.0f, 0.0f, 0.0f, 0.0f);
    } else {
      float4 v = x4[tid];
      if (mm[0]) v.x = 0.0f;
      if (mm[1]) v.y = 0.0f;
      if (mm[2]) v.z = 0.0f;
      if (mm[3]) v.w = 0.0f;
      o4[tid] = v;
    }
  } else {
    // ---- masks path (float 1.0/0.0). 250 % 4 != 0 so compute b per element
    // (stores are still contiguous float4).
    int t = tid - NV4X;
    int f = t << 2;
    float vv[4];
#pragma unroll
    for (int j = 0; j < 4; ++j) {
      int i = f + j;
      int b = i / SEQ;
      int p = i - b * SEQ;
      bool m = ((unsigned)(p - starts[b * 3 + 0]) < (unsigned)SPAN) ||
               ((unsigned)(p - starts[b * 3 + 1]) < (unsigned)SPAN) ||
               ((unsigned)(p - starts[b * 3 + 2]) < (unsigned)SPAN);
      vv[j] = m ? 1.0f : 0.0f;
    }
    m4[t] = make_float4(vv[0], vv[1], vv[2], vv[3]);
  }
}

}  // namespace

extern "C" void kernel_launch(void* const* d_in, const int* in_sizes, int n_in,
                              void* d_out, int out_size, void* d_ws, size_t ws_size,
                              hipStream_t stream) {
  const float* x = (const float*)d_in[0];
  float* out = (float*)d_out;                          // masked_x: 16384*12*250
  float* mask_out = out + (size_t)NB * NCH * SEQ;      // masks:    16384*250
  int* starts = (int*)d_ws;                            // 49152 ints (192 KiB)

  k_starts<<<(NB * NSPANS + 255) / 256, 256, 0, stream>>>(starts);
  k_fused<<<NV4T / 256, 256, 0, stream>>>(
      (const float4*)x, (float4*)out, (float4*)mask_out, starts);
}

// Round 2
// 336.252 us; speedup vs baseline: 1.0205x; 1.0084x over previous
//
#include <hip/hip_runtime.h>
#include <stdint.h>

namespace {

constexpr int SEQ    = 250;
constexpr int SPAN   = 50;
constexpr int NSPANS = 3;
constexpr int NATT   = 15;
constexpr int QS     = 95;   // QRS_START
constexpr int QE     = 155;  // QRS_END
constexpr int NB     = 16384;
constexpr int NCH    = 12;
constexpr uint32_t HI = 200; // exclusive upper bound for starts

struct U2 { uint32_t a, b; };

// Threefry-2x32, 20 rounds — bit-exact replica of jax/_src/prng.py
__host__ __device__ constexpr U2 tf2x32(uint32_t k0, uint32_t k1,
                                        uint32_t x0, uint32_t x1) {
  uint32_t ks[3] = { k0, k1, k0 ^ k1 ^ 0x1BD11BDAu };
  uint32_t rot[2][4] = { {13u, 15u, 26u, 6u}, {17u, 29u, 16u, 24u} };
  x0 += ks[0];
  x1 += ks[1];
  for (int i = 0; i < 5; ++i) {
    for (int j = 0; j < 4; ++j) {
      uint32_t r = rot[i & 1][j];
      x0 += x1;
      x1 = (x1 << r) | (x1 >> (32u - r));
      x1 ^= x0;
    }
    x0 += ks[(i + 1) % 3];
    x1 += ks[(i + 2) % 3] + (uint32_t)(i + 1);
  }
  return U2{x0, x1};
}

// ---- PARTITIONABLE threefry semantics (jax_threefry_partitionable=True):
//   split(key, n): subkey j = (tf(key,0,j).a, tf(key,0,j).b)   [no XOR]
//   random_bits(key, 32, shape): out[i] = tf(key,0,i).a ^ tf(key,0,i).b [XOR]
//
// jax.random.key(42) => raw key (0, 42)
constexpr U2 SK1 = tf2x32(0u, 42u, 0u, 0u);  // k1: uniform(use_physio)
constexpr U2 SK2 = tf2x32(0u, 42u, 0u, 1u);  // k2: candidate randint
constexpr U2 SK3 = tf2x32(0u, 42u, 0u, 2u);  // k3: fallback randint

// randint's internal split(key, 2): hi-bits key counter (0,0), lo-bits (0,1)
constexpr U2 K2H = tf2x32(SK2.a, SK2.b, 0u, 0u);
constexpr U2 K2L = tf2x32(SK2.a, SK2.b, 0u, 1u);
constexpr U2 K3H = tf2x32(SK3.a, SK3.b, 0u, 0u);
constexpr U2 K3L = tf2x32(SK3.a, SK3.b, 0u, 1u);

// 32-bit random bits draw, partitionable path: XOR of both output words
__device__ __forceinline__ uint32_t rbit(U2 k, uint32_t idx) {
  U2 r = tf2x32(k.a, k.b, 0u, idx);
  return r.a ^ r.b;
}

// jax randint(0,200): multiplier = (2^16 % 200)^2 % 200 = 96
__device__ __forceinline__ uint32_t draw200(uint32_t h, uint32_t l) {
  return ((h % HI) * 96u + (l % HI)) % HI;
}

// Span start for flat unit u = b*NSPANS + s. Same semantics as the previous
// standalone k_starts kernel (rejection loop, first-valid, fallback draw).
__device__ __forceinline__ int compute_start(uint32_t u) {
  // use_physio = uniform(k1) < 0.8 ; u = bitcast((bits>>9)|0x3f800000) - 1
  uint32_t ub = rbit(SK1, u);
  float uu = __uint_as_float((ub >> 9) | 0x3f800000u) - 1.0f;
  bool physio = (uu < 0.8f);

  for (int a = 0; a < NATT; ++a) {
    uint32_t idx = u * (uint32_t)NATT + (uint32_t)a;  // flat (B,S,A) index
    uint32_t h = rbit(K2H, idx);
    uint32_t l = rbit(K2L, idx);
    int cand = (int)draw200(h, l);
    // ends = min(cand+50, 250) <= 249; no_overlap = (end<=95) | (cand>=155)
    bool no_ov = (cand + SPAN <= QS) || (cand >= QE);
    if (no_ov || !physio) return cand;  // argmax = first valid
  }
  uint32_t h = rbit(K3H, u);
  uint32_t l = rbit(K3L, u);
  return (int)draw200(h, l);
}

// Single fused kernel: one block == one batch.
//   phase 1: threads 0..2 compute this batch's 3 span starts -> LDS
//            (zero cross-block redundancy; ~1.4K wave-instr avg, hidden
//             under the memory phase of neighbor blocks)
//   phase 2: masked_x — 750 float4 per batch (3000 floats, 16B-aligned
//            since b*3000*4 % 16 == 0). Read-skip: fully-masked float4
//            stores zeros without loading x (masked runs are 200-600B,
//            so many 128B lines are never fetched).
//   phase 3: masks — 125 float2 per batch (250 floats; odd batches are
//            only 8B-aligned, so float2 is the widest safe store).
__global__ __launch_bounds__(256)
void k_all(const float4* __restrict__ x4, float4* __restrict__ o4,
           float2* __restrict__ m2) {
  __shared__ int ss[NSPANS];
  const int b = blockIdx.x;
  const int t = threadIdx.x;

  if (t < NSPANS) ss[t] = compute_start((uint32_t)(b * NSPANS + t));
  __syncthreads();
  const int s0 = ss[0], s1 = ss[1], s2 = ss[2];

  // ---- masked_x: 750 float4 per batch
  const float4* xb = x4 + (size_t)b * (NCH * SEQ / 4);
  float4*       ob = o4 + (size_t)b * (NCH * SEQ / 4);
  for (int i = t; i < NCH * SEQ / 4; i += 256) {
    int pos0 = (i << 2) % SEQ;
    bool mm[4];
    int nmask = 0;
#pragma unroll
    for (int j = 0; j < 4; ++j) {
      int p = pos0 + j;
      if (p >= SEQ) p -= SEQ;  // wrap into next channel row (same batch)
      bool m = ((unsigned)(p - s0) < (unsigned)SPAN) ||
               ((unsigned)(p - s1) < (unsigned)SPAN) ||
               ((unsigned)(p - s2) < (unsigned)SPAN);
      mm[j] = m;
      nmask += (int)m;
    }
    if (nmask == 4) {
      ob[i] = make_float4(0.0f, 0.0f, 0.0f, 0.0f);  // no x read needed
    } else {
      float4 v = xb[i];
      if (mm[0]) v.x = 0.0f;
      if (mm[1]) v.y = 0.0f;
      if (mm[2]) v.z = 0.0f;
      if (mm[3]) v.w = 0.0f;
      ob[i] = v;
    }
  }

  // ---- masks: 125 float2 per batch (float 1.0/0.0)
  if (t < SEQ / 2) {
    int p0 = t * 2;
    bool ma = ((unsigned)(p0 - s0) < (unsigned)SPAN) ||
              ((unsigned)(p0 - s1) < (unsigned)SPAN) ||
              ((unsigned)(p0 - s2) < (unsigned)SPAN);
    int p1 = p0 + 1;
    bool mb = ((unsigned)(p1 - s0) < (unsigned)SPAN) ||
              ((unsigned)(p1 - s1) < (unsigned)SPAN) ||
              ((unsigned)(p1 - s2) < (unsigned)SPAN);
    m2[(size_t)b * (SEQ / 2) + t] = make_float2(ma ? 1.0f : 0.0f,
                                                mb ? 1.0f : 0.0f);
  }
}

}  // namespace

extern "C" void kernel_launch(void* const* d_in, const int* in_sizes, int n_in,
                              void* d_out, int out_size, void* d_ws, size_t ws_size,
                              hipStream_t stream) {
  const float* x = (const float*)d_in[0];
  float* out = (float*)d_out;                          // masked_x: 16384*12*250
  float* mask_out = out + (size_t)NB * NCH * SEQ;      // masks:    16384*250

  k_all<<<NB, 256, 0, stream>>>(
      (const float4*)x, (float4*)out, (float2*)mask_out);
}

// Round 4
// 323.247 us; speedup vs baseline: 1.0615x; 1.0402x over previous
//
#include <hip/hip_runtime.h>
#include <stdint.h>

namespace {

constexpr int SEQ    = 250;
constexpr int SPAN   = 50;
constexpr int NSPANS = 3;
constexpr int NATT   = 15;
constexpr int QS     = 95;   // QRS_START
constexpr int QE     = 155;  // QRS_END
constexpr int NB     = 16384;
constexpr int NCH    = 12;
constexpr uint32_t HI = 200; // exclusive upper bound for starts

typedef float f32x4 __attribute__((ext_vector_type(4)));
typedef float f32x2 __attribute__((ext_vector_type(2)));

struct U2 { uint32_t a, b; };

// Threefry-2x32, 20 rounds — bit-exact replica of jax/_src/prng.py
__host__ __device__ constexpr U2 tf2x32(uint32_t k0, uint32_t k1,
                                        uint32_t x0, uint32_t x1) {
  uint32_t ks[3] = { k0, k1, k0 ^ k1 ^ 0x1BD11BDAu };
  uint32_t rot[2][4] = { {13u, 15u, 26u, 6u}, {17u, 29u, 16u, 24u} };
  x0 += ks[0];
  x1 += ks[1];
  for (int i = 0; i < 5; ++i) {
    for (int j = 0; j < 4; ++j) {
      uint32_t r = rot[i & 1][j];
      x0 += x1;
      x1 = (x1 << r) | (x1 >> (32u - r));
      x1 ^= x0;
    }
    x0 += ks[(i + 1) % 3];
    x1 += ks[(i + 2) % 3] + (uint32_t)(i + 1);
  }
  return U2{x0, x1};
}

// ---- PARTITIONABLE threefry semantics (jax_threefry_partitionable=True):
//   split(key, n): subkey j = (tf(key,0,j).a, tf(key,0,j).b)   [no XOR]
//   random_bits(key, 32, shape): out[i] = tf(key,0,i).a ^ tf(key,0,i).b [XOR]
//
// jax.random.key(42) => raw key (0, 42)
constexpr U2 SK1 = tf2x32(0u, 42u, 0u, 0u);  // k1: uniform(use_physio)
constexpr U2 SK2 = tf2x32(0u, 42u, 0u, 1u);  // k2: candidate randint
constexpr U2 SK3 = tf2x32(0u, 42u, 0u, 2u);  // k3: fallback randint

// randint's internal split(key, 2): hi-bits key counter (0,0), lo-bits (0,1)
constexpr U2 K2H = tf2x32(SK2.a, SK2.b, 0u, 0u);
constexpr U2 K2L = tf2x32(SK2.a, SK2.b, 0u, 1u);
constexpr U2 K3H = tf2x32(SK3.a, SK3.b, 0u, 0u);
constexpr U2 K3L = tf2x32(SK3.a, SK3.b, 0u, 1u);

// 32-bit random bits draw, partitionable path: XOR of both output words
__device__ __forceinline__ uint32_t rbit(U2 k, uint32_t idx) {
  U2 r = tf2x32(k.a, k.b, 0u, idx);
  return r.a ^ r.b;
}

// jax randint(0,200): multiplier = (2^16 % 200)^2 % 200 = 96
__device__ __forceinline__ uint32_t draw200(uint32_t h, uint32_t l) {
  return ((h % HI) * 96u + (l % HI)) % HI;
}

// Single fused kernel: one block == one batch.
//
// phase 1 (wave 0 only, LANE-PARALLEL): lanes t = s*15+a (45 active) each
//   evaluate ONE rejection attempt (2 threefry) in parallel; one __ballot,
//   then the first-valid lane of each span's 15-bit window writes ss[s].
//   Serial chain ~300 VALU instr flat (was ~700-3300 with the 3-lane serial
//   loop) -> the __syncthreads bubble that was throttling memory-wave
//   concurrency (kernel ran ~5.2 TB/s vs 6.4 achievable) mostly vanishes.
//   argmax-first-valid semantics preserved: if no attempt valid -> fallback
//   draw from k3 (prob ~9e-5); non-physio spans pick attempt 0 (all valid).
//
// phase 2: masks — 125 f32x2 per batch (odd batches only 8B-aligned).
// phase 3: masked_x — 750 f32x4 per batch. Read-skip: fully-masked f32x4
//   stores zeros without loading x (masked runs are 200-600B, so many 128B
//   lines are never fetched). Nontemporal hints: pure streaming, no reuse.
__global__ __launch_bounds__(256)
void k_all(const f32x4* __restrict__ x4, f32x4* __restrict__ o4,
           f32x2* __restrict__ m2) {
  __shared__ int ss[NSPANS];
  const int b = blockIdx.x;
  const int t = threadIdx.x;

  if (t < 64) {  // wave 0
    const int s = t / NATT;            // 0..4 (only 0..2 meaningful)
    const int a = t - s * NATT;        // attempt index within span
    const bool lane_ok = (t < NSPANS * NATT);  // 45 active lanes
    const uint32_t u = (uint32_t)(b * NSPANS + (lane_ok ? s : 0));

    bool valid = false;
    int cand = 0;
    if (lane_ok) {
      // use_physio = uniform(k1) < 0.8 (redundant across the span's 15 lanes)
      uint32_t ub = rbit(SK1, u);
      float uu = __uint_as_float((ub >> 9) | 0x3f800000u) - 1.0f;
      bool physio = (uu < 0.8f);
      uint32_t idx = u * (uint32_t)NATT + (uint32_t)a;  // flat (B,S,A) index
      cand = (int)draw200(rbit(K2H, idx), rbit(K2L, idx));
      // ends = cand+50 (<=249); no_overlap = (end<=95) | (cand>=155)
      bool no_ov = (cand + SPAN <= QS) || (cand >= QE);
      valid = no_ov || !physio;
    }

    uint64_t m = __ballot(valid);  // all 64 lanes of wave 0 participate
    if (lane_ok) {
      uint32_t sm = (uint32_t)(m >> (s * NATT)) & 0x7FFFu;  // my span's window
      bool i_am_first = valid && ((sm & ((1u << a) - 1u)) == 0u);
      if (i_am_first) ss[s] = cand;                 // argmax = first valid
      if (a == 0 && sm == 0u) {                     // no valid attempt
        ss[s] = (int)draw200(rbit(K3H, u), rbit(K3L, u));
      }
    }
  }
  __syncthreads();
  const int s0 = ss[0], s1 = ss[1], s2 = ss[2];

  // ---- masks first (stores issue while other waves start the x loop)
  if (t < SEQ / 2) {
    int p0 = t * 2;
    bool ma = ((unsigned)(p0 - s0) < (unsigned)SPAN) ||
              ((unsigned)(p0 - s1) < (unsigned)SPAN) ||
              ((unsigned)(p0 - s2) < (unsigned)SPAN);
    int p1 = p0 + 1;
    bool mb = ((unsigned)(p1 - s0) < (unsigned)SPAN) ||
              ((unsigned)(p1 - s1) < (unsigned)SPAN) ||
              ((unsigned)(p1 - s2) < (unsigned)SPAN);
    f32x2 mv = { ma ? 1.0f : 0.0f, mb ? 1.0f : 0.0f };
    __builtin_nontemporal_store(mv, &m2[(size_t)b * (SEQ / 2) + t]);
  }

  // ---- masked_x: 750 f32x4 per batch
  const f32x4* xb = x4 + (size_t)b * (NCH * SEQ / 4);
  f32x4*       ob = o4 + (size_t)b * (NCH * SEQ / 4);
  for (int i = t; i < NCH * SEQ / 4; i += 256) {
    int pos0 = (i << 2) % SEQ;
    bool mm[4];
    int nmask = 0;
#pragma unroll
    for (int j = 0; j < 4; ++j) {
      int p = pos0 + j;
      if (p >= SEQ) p -= SEQ;  // wrap into next channel row (same batch)
      bool m = ((unsigned)(p - s0) < (unsigned)SPAN) ||
               ((unsigned)(p - s1) < (unsigned)SPAN) ||
               ((unsigned)(p - s2) < (unsigned)SPAN);
      mm[j] = m;
      nmask += (int)m;
    }
    if (nmask == 4) {
      // fully masked: no x read needed
      f32x4 z = { 0.0f, 0.0f, 0.0f, 0.0f };
      __builtin_nontemporal_store(z, &ob[i]);
    } else {
      f32x4 v = __builtin_nontemporal_load(&xb[i]);
      if (mm[0]) v.x = 0.0f;
      if (mm[1]) v.y = 0.0f;
      if (mm[2]) v.z = 0.0f;
      if (mm[3]) v.w = 0.0f;
      __builtin_nontemporal_store(v, &ob[i]);
    }
  }
}

}  // namespace

extern "C" void kernel_launch(void* const* d_in, const int* in_sizes, int n_in,
                              void* d_out, int out_size, void* d_ws, size_t ws_size,
                              hipStream_t stream) {
  const float* x = (const float*)d_in[0];
  float* out = (float*)d_out;                          // masked_x: 16384*12*250
  float* mask_out = out + (size_t)NB * NCH * SEQ;      // masks:    16384*250

  k_all<<<NB, 256, 0, stream>>>(
      (const f32x4*)x, (f32x4*)out, (f32x2*)mask_out);
}